// Round 3
// baseline (247.515 us; speedup 1.0000x reference)
//
#include <hip/hip_runtime.h>
#include <hip/hip_bf16.h>

#define IN_DIM 98304

typedef short bh8 __attribute__((ext_vector_type(8)));
typedef float f32x4 __attribute__((ext_vector_type(4)));
typedef unsigned short u16x8 __attribute__((ext_vector_type(8)));
typedef unsigned short u16x4 __attribute__((ext_vector_type(4)));

__device__ __forceinline__ unsigned short f2bf(float f) {
  __hip_bfloat16 h = __float2bfloat16(f);
  return __builtin_bit_cast(unsigned short, h);
}

__device__ __forceinline__ void bfly(float2& a, float2& b, float wr, float wi) {
  float tr = wr * b.x - wi * b.y;
  float ti = wr * b.y + wi * b.x;
  b.x = a.x - tr; b.y = a.y - ti;
  a.x += tr; a.y += ti;
}

__device__ __forceinline__ float2 cmul(float2 a, float2 w) {
  return make_float2(a.x * w.x - a.y * w.y, a.x * w.y + a.y * w.x);
}

// 16-point FFT, input bit-reversed in v[], output natural order.
__device__ __forceinline__ void fft16(float2* v) {
  const float C8 = 0.70710678118654752f;
  const float C161 = 0.92387953251128674f, S161 = 0.38268343236508977f;
#pragma unroll
  for (int i = 0; i < 16; i += 2) bfly(v[i], v[i + 1], 1.f, 0.f);
#pragma unroll
  for (int i = 0; i < 16; i += 4) {
    bfly(v[i], v[i + 2], 1.f, 0.f);
    bfly(v[i + 1], v[i + 3], 0.f, -1.f);
  }
  {
    const float w8r[4] = {1.f, C8, 0.f, -C8};
    const float w8i[4] = {0.f, -C8, -1.f, -C8};
#pragma unroll
    for (int i = 0; i < 16; i += 8) {
#pragma unroll
      for (int j = 0; j < 4; ++j) bfly(v[i + j], v[i + j + 4], w8r[j], w8i[j]);
    }
  }
  {
    const float w16r[8] = {1.f, C161, C8, S161, 0.f, -S161, -C8, -C161};
    const float w16i[8] = {0.f, -S161, -C8, -C161, -1.f, -C161, -C8, -S161};
#pragma unroll
    for (int j = 0; j < 8; ++j) bfly(v[j], v[j + 8], w16r[j], w16i[j]);
  }
}

// 8-point FFT, input bit-reversed in v[], output natural order.
__device__ __forceinline__ void fft8(float2* v) {
  const float C8 = 0.70710678118654752f;
#pragma unroll
  for (int i = 0; i < 8; i += 2) bfly(v[i], v[i + 1], 1.f, 0.f);
#pragma unroll
  for (int i = 0; i < 8; i += 4) {
    bfly(v[i], v[i + 2], 1.f, 0.f);
    bfly(v[i + 1], v[i + 3], 0.f, -1.f);
  }
  bfly(v[0], v[4], 1.f, 0.f);
  bfly(v[1], v[5], C8, -C8);
  bfly(v[2], v[6], 0.f, -1.f);
  bfly(v[3], v[7], -C8, -C8);
}

// swizzled LDS index (float2 units)
__device__ __forceinline__ int IDX(int r, int cc) {
  return (r << 7) + (cc ^ ((r & 7) << 1));
}

// ---------------------------------------------------------------------------
// Kernel 1: 128x128 FFT2 + fftshift + amp/phase -> bf16 feats, PLUS
// (optional) W1 fp32->bf16 conversion streamed through the FFT's idle
// memory pipe: each of the 768 blocks converts a 65536-float slice in 4
// chunks, loads issued one FFT-stage ahead of the stores.
// ---------------------------------------------------------------------------
__global__ __launch_bounds__(512) void fft_feats_kernel(
    const float* __restrict__ img, unsigned short* __restrict__ feats,
    const float* __restrict__ W1, unsigned short* __restrict__ wbf) {
  __shared__ float2 sm[16384];
  __shared__ float2 tw[128];
  const int tid = threadIdx.x;
  const int c = blockIdx.x, b = blockIdx.y;
  const float* src = img + ((size_t)(b * 3 + c) << 14);

  static const int BR4[16] = {0, 8, 4, 12, 2, 10, 6, 14, 1, 9, 5, 13, 3, 11, 7, 15};
  static const int BR3[8] = {0, 4, 2, 6, 1, 5, 3, 7};

  const size_t cslice = ((size_t)(b * 3 + c)) << 16;  // 65536 floats per block
  float4 cf[8];
#define CONV_ISSUE(ch)                                                        \
  if (wbf) {                                                                  \
    const float4* p = reinterpret_cast<const float4*>(W1 + cslice + (ch)*16384); \
    _Pragma("unroll") for (int i = 0; i < 8; ++i) cf[i] = p[i * 512 + tid];   \
  }
#define CONV_STORE(ch)                                                        \
  if (wbf) {                                                                  \
    unsigned short* q = wbf + cslice + (ch)*16384;                            \
    _Pragma("unroll") for (int i = 0; i < 8; ++i) {                           \
      u16x4 v4 = {f2bf(cf[i].x), f2bf(cf[i].y), f2bf(cf[i].z), f2bf(cf[i].w)}; \
      *reinterpret_cast<u16x4*>(q + ((i * 512 + tid) << 2)) = v4;             \
    }                                                                         \
  }

  CONV_ISSUE(0);

  if (tid < 128) {
    float sv, cv;
    sincosf(-6.28318530717958647692f * (float)tid / 128.0f, &sv, &cv);
    tw[tid] = make_float2(cv, sv);
  }
  // load 128x128 reals, coalesced float4, as (re,0) complex
  for (int i4 = tid; i4 < 4096; i4 += 512) {
    float4 x = *reinterpret_cast<const float4*>(src + (i4 << 2));
    int r = i4 >> 5, cc = (i4 << 2) & 127;
    *reinterpret_cast<float4*>(&sm[IDX(r, cc)]) = make_float4(x.x, 0.f, x.y, 0.f);
    *reinterpret_cast<float4*>(&sm[IDX(r, cc + 2)]) = make_float4(x.z, 0.f, x.w, 0.f);
  }
  __syncthreads();

  // ---- row pass, stage 1
#pragma unroll
  for (int it = 0; it < 2; ++it) {
    int ss = it * 512 + tid;
    int r = ss >> 3, n2 = ss & 7;
    float2 v[16];
#pragma unroll
    for (int j = 0; j < 16; ++j) v[j] = sm[IDX(r, (BR4[j] << 3) + n2)];
    fft16(v);
#pragma unroll
    for (int k1 = 1; k1 < 16; ++k1) v[k1] = cmul(v[k1], tw[n2 * k1]);
#pragma unroll
    for (int k1 = 0; k1 < 16; ++k1) sm[IDX(r, (k1 << 3) + n2)] = v[k1];
  }
  __syncthreads();

  CONV_STORE(0);
  CONV_ISSUE(1);

  // ---- row pass, stage 2
#pragma unroll
  for (int it = 0; it < 2; ++it) {
    int ss = it * 512 + tid;
    int r = ss >> 3, t8 = ss & 7;
    float2 u0[8], u1[8];
#pragma unroll
    for (int j = 0; j < 8; ++j) {
      u0[j] = sm[IDX(r, (t8 << 3) + BR3[j])];
      u1[j] = sm[IDX(r, ((t8 + 8) << 3) + BR3[j])];
    }
    __syncthreads();  // all reads of this row-group before any writes to it
    fft8(u0);
    fft8(u1);
#pragma unroll
    for (int k2 = 0; k2 < 8; ++k2) {
      sm[IDX(r, t8 + (k2 << 4))] = u0[k2];
      sm[IDX(r, t8 + 8 + (k2 << 4))] = u1[k2];
    }
  }
  __syncthreads();

  CONV_STORE(1);
  CONV_ISSUE(2);

  // ---- col pass, stage 1
#pragma unroll
  for (int it = 0; it < 2; ++it) {
    int ss = it * 512 + tid;
    int col = ss & 127, n2 = ss >> 7;
    float2 v[16];
#pragma unroll
    for (int j = 0; j < 16; ++j) v[j] = sm[IDX((BR4[j] << 3) + n2, col)];
    fft16(v);
#pragma unroll
    for (int k1 = 1; k1 < 16; ++k1) v[k1] = cmul(v[k1], tw[n2 * k1]);
#pragma unroll
    for (int k1 = 0; k1 < 16; ++k1) sm[IDX((k1 << 3) + n2, col)] = v[k1];
  }
  __syncthreads();

  CONV_STORE(2);
  CONV_ISSUE(3);

  // ---- col pass, stage 2 + fftshift + amp/phase + global write
  unsigned short* dst = feats + (size_t)b * IN_DIM + c * 32768;
#pragma unroll
  for (int it = 0; it < 2; ++it) {
    int ss = it * 512 + tid;
    int col = ss & 127, t8 = ss >> 7;
    float2 u0[8], u1[8];
#pragma unroll
    for (int j = 0; j < 8; ++j) {
      u0[j] = sm[IDX((t8 << 3) + BR3[j], col)];
      u1[j] = sm[IDX(((t8 + 8) << 3) + BR3[j], col)];
    }
    fft8(u0);
    fft8(u1);
    int ow = col ^ 64;
#pragma unroll
    for (int k2 = 0; k2 < 8; ++k2) {
      int oh0 = (t8 + (k2 << 4)) ^ 64;
      int oh1 = (t8 + 8 + (k2 << 4)) ^ 64;
      float a0 = sqrtf(u0[k2].x * u0[k2].x + u0[k2].y * u0[k2].y);
      float p0 = atan2f(u0[k2].y, u0[k2].x);
      float a1 = sqrtf(u1[k2].x * u1[k2].x + u1[k2].y * u1[k2].y);
      float p1 = atan2f(u1[k2].y, u1[k2].x);
      dst[(oh0 << 7) + ow] = f2bf(a0);
      dst[16384 + (oh0 << 7) + ow] = f2bf(p0);
      dst[(oh1 << 7) + ow] = f2bf(a1);
      dst[16384 + (oh1 << 7) + ow] = f2bf(p1);
    }
  }

  CONV_STORE(3);
#undef CONV_ISSUE
#undef CONV_STORE
}

// ---------------------------------------------------------------------------
// Kernel 2: layer-1 GEMM, split-K + split-M, software-pipelined.
// grid (8 nt, 2 mt, S ks): tile MT=128, NT=64, kchunk = IN_DIM/S.
// WBF=true: W1 already bf16 (wbf). WBF=false: W1 fp32, convert on the fly.
// ---------------------------------------------------------------------------
template <bool WBF>
__global__ __launch_bounds__(256, 2) void gemm1_kernel(
    const unsigned short* __restrict__ feats, const void* __restrict__ w1p,
    float* __restrict__ partial, int kchunk) {
  __shared__ __align__(16) unsigned short Asm[128 * 40];  // pitch 40 (pad 8)
  __shared__ __align__(16) unsigned short Bsm[64 * 40];
  const int tid = threadIdx.x;
  const int nt = blockIdx.x;
  const int m0 = blockIdx.y * 128;
  const int ks = blockIdx.z;
  const int wv = tid >> 6, lane = tid & 63;
  const int wr = wv >> 1, wc = wv & 1;  // wave tile 64x32
  const int n0 = nt * 64;
  const size_t k0 = (size_t)ks * kchunk;
  const int iters = kchunk >> 5;

  f32x4 acc[4][2];
#pragma unroll
  for (int i = 0; i < 4; ++i)
#pragma unroll
    for (int j = 0; j < 2; ++j) acc[i][j] = (f32x4){0.f, 0.f, 0.f, 0.f};

  const int ar = tid >> 1;              // 0..127
  const int a16 = (tid & 1) * 16;       // k offset
  const int brow = tid >> 2;            // 0..63
  const int bk8 = (tid & 3) * 8;

  u16x8 av0, av1, bv;
  float4 f0, f1;
  {  // prefetch iteration 0
    const unsigned short* ap = feats + (size_t)(m0 + ar) * IN_DIM + k0 + a16;
    av0 = *reinterpret_cast<const u16x8*>(ap);
    av1 = *reinterpret_cast<const u16x8*>(ap + 8);
    if constexpr (WBF) {
      bv = *reinterpret_cast<const u16x8*>(
          (const unsigned short*)w1p + (size_t)(n0 + brow) * IN_DIM + k0 + bk8);
    } else {
      const float* wsrc = (const float*)w1p + (size_t)(n0 + brow) * IN_DIM + k0 + bk8;
      f0 = *reinterpret_cast<const float4*>(wsrc);
      f1 = *reinterpret_cast<const float4*>(wsrc + 4);
    }
  }

  for (int kk = 0; kk < iters; ++kk) {
    __syncthreads();  // previous iteration's LDS frag reads complete
    *reinterpret_cast<u16x8*>(&Asm[ar * 40 + a16]) = av0;
    *reinterpret_cast<u16x8*>(&Asm[ar * 40 + a16 + 8]) = av1;
    if constexpr (WBF) {
      *reinterpret_cast<u16x8*>(&Bsm[brow * 40 + bk8]) = bv;
    } else {
      u16x8 bw;
      bw[0] = f2bf(f0.x); bw[1] = f2bf(f0.y); bw[2] = f2bf(f0.z); bw[3] = f2bf(f0.w);
      bw[4] = f2bf(f1.x); bw[5] = f2bf(f1.y); bw[6] = f2bf(f1.z); bw[7] = f2bf(f1.w);
      *reinterpret_cast<u16x8*>(&Bsm[brow * 40 + bk8]) = bw;
    }
    __syncthreads();  // tile ready

    if (kk + 1 < iters) {  // prefetch next tile; overlaps MFMA below
      size_t kb = k0 + (size_t)(kk + 1) * 32;
      const unsigned short* ap = feats + (size_t)(m0 + ar) * IN_DIM + kb + a16;
      av0 = *reinterpret_cast<const u16x8*>(ap);
      av1 = *reinterpret_cast<const u16x8*>(ap + 8);
      if constexpr (WBF) {
        bv = *reinterpret_cast<const u16x8*>(
            (const unsigned short*)w1p + (size_t)(n0 + brow) * IN_DIM + kb + bk8);
      } else {
        const float* wsrc = (const float*)w1p + (size_t)(n0 + brow) * IN_DIM + kb + bk8;
        f0 = *reinterpret_cast<const float4*>(wsrc);
        f1 = *reinterpret_cast<const float4*>(wsrc + 4);
      }
    }

    const int rm = lane & 15, ko = (lane >> 4) * 8;
    bh8 a[4], bf[2];
#pragma unroll
    for (int i = 0; i < 4; ++i)
      a[i] = *reinterpret_cast<const bh8*>(&Asm[(wr * 64 + i * 16 + rm) * 40 + ko]);
#pragma unroll
    for (int j = 0; j < 2; ++j)
      bf[j] = *reinterpret_cast<const bh8*>(&Bsm[(wc * 32 + j * 16 + rm) * 40 + ko]);
#pragma unroll
    for (int i = 0; i < 4; ++i)
#pragma unroll
      for (int j = 0; j < 2; ++j)
        acc[i][j] =
            __builtin_amdgcn_mfma_f32_16x16x32_bf16(a[i], bf[j], acc[i][j], 0, 0, 0);
  }

  // epilogue: C/D layout col=lane&15, row=(lane>>4)*4+reg
  const int rm = lane & 15, rg = lane >> 4;
  float* pbase = partial + ((size_t)ks << 17);
#pragma unroll
  for (int i = 0; i < 4; ++i) {
#pragma unroll
    for (int j = 0; j < 2; ++j) {
      int n = n0 + wc * 32 + j * 16 + rm;
#pragma unroll
      for (int r = 0; r < 4; ++r) {
        int m = m0 + wr * 64 + i * 16 + rg * 4 + r;
        pbase[((size_t)m << 9) + n] = acc[i][j][r];
      }
    }
  }
}

// ---------------------------------------------------------------------------
// Kernel 3: reduce split-K partials + bias + ReLU -> x1 [256][512] fp32
// ---------------------------------------------------------------------------
__global__ __launch_bounds__(256) void reduce1_kernel(
    const float* __restrict__ partial, const float* __restrict__ b1,
    float* __restrict__ x1, int S) {
  int i = blockIdx.x * 256 + threadIdx.x;  // 0..131071
  float s = b1[i & 511];
  for (int p = 0; p < S; ++p) s += partial[((size_t)p << 17) + i];
  x1[i] = fmaxf(s, 0.0f);
}

// ---------------------------------------------------------------------------
// Kernel 4: x2 = relu(x1 @ W2^T + b2)
// ---------------------------------------------------------------------------
__global__ __launch_bounds__(256) void fc2_kernel(
    const float* __restrict__ x1, const float* __restrict__ W2,
    const float* __restrict__ b2, float* __restrict__ x2) {
  __shared__ float xs[512];
  int b = blockIdx.x, n = threadIdx.x;
  xs[n] = x1[b * 512 + n];
  xs[n + 256] = x1[b * 512 + 256 + n];
  __syncthreads();
  float acc = b2[n];
  const float* wr = W2 + (size_t)n * 512;
#pragma unroll 4
  for (int k = 0; k < 512; k += 4) {
    float4 w = *reinterpret_cast<const float4*>(wr + k);
    acc += xs[k] * w.x + xs[k + 1] * w.y + xs[k + 2] * w.z + xs[k + 3] * w.w;
  }
  x2[b * 256 + n] = fmaxf(acc, 0.0f);
}

// ---------------------------------------------------------------------------
// Kernel 5: out = x2 @ W3^T + b3
// ---------------------------------------------------------------------------
__global__ __launch_bounds__(128) void fc3_kernel(
    const float* __restrict__ x2, const float* __restrict__ W3,
    const float* __restrict__ b3, float* __restrict__ out) {
  __shared__ float xs[256];
  int b = blockIdx.x, n = threadIdx.x;
  xs[n] = x2[b * 256 + n];
  xs[n + 128] = x2[b * 256 + 128 + n];
  __syncthreads();
  float acc = b3[n];
  const float* wr = W3 + (size_t)n * 256;
#pragma unroll 4
  for (int k = 0; k < 256; k += 4) {
    float4 w = *reinterpret_cast<const float4*>(wr + k);
    acc += xs[k] * w.x + xs[k + 1] * w.y + xs[k + 2] * w.z + xs[k + 3] * w.w;
  }
  out[b * 128 + n] = acc;
}

extern "C" void kernel_launch(void* const* d_in, const int* in_sizes, int n_in,
                              void* d_out, int out_size, void* d_ws, size_t ws_size,
                              hipStream_t stream) {
  const float* img = (const float*)d_in[0];
  const float* W1 = (const float*)d_in[1];
  const float* b1 = (const float*)d_in[2];
  const float* W2 = (const float*)d_in[3];
  const float* b2 = (const float*)d_in[4];
  const float* W3 = (const float*)d_in[5];
  const float* b3 = (const float*)d_in[6];
  float* out = (float*)d_out;
  char* ws = (char*)d_ws;

  const size_t FEATS_B = 50331648ull;   // bf16 [256][98304]
  const size_t WBF_B = 100663296ull;    // bf16 [512][98304]
  const size_t need_bf = FEATS_B + WBF_B + 64ull * 524288 + 786432;   // 185.3 MB
  const size_t need_f64 = FEATS_B + 64ull * 524288 + 786432;          // 84.7 MB

  unsigned short* feats = (unsigned short*)ws;

  if (ws_size >= need_bf) {
    // bf16-W1 path, S=64
    unsigned short* wbf = (unsigned short*)(ws + FEATS_B);
    float* partial = (float*)(ws + FEATS_B + WBF_B);
    float* x1 = partial + 64ull * 131072;
    float* x2 = x1 + 131072;
    hipLaunchKernelGGL(fft_feats_kernel, dim3(3, 256), dim3(512), 0, stream,
                       img, feats, W1, wbf);
    hipLaunchKernelGGL(HIP_KERNEL_NAME(gemm1_kernel<true>), dim3(8, 2, 64),
                       dim3(256), 0, stream, feats, (const void*)wbf, partial, 1536);
    hipLaunchKernelGGL(reduce1_kernel, dim3(512), dim3(256), 0, stream, partial, b1, x1, 64);
    hipLaunchKernelGGL(fc2_kernel, dim3(256), dim3(256), 0, stream, x1, W2, b2, x2);
    hipLaunchKernelGGL(fc3_kernel, dim3(256), dim3(128), 0, stream, x2, W3, b3, out);
  } else {
    // fp32-W1 path
    const int S = (ws_size >= need_f64) ? 64 : 32;
    const int kchunk = IN_DIM / S;
    float* partial = (float*)(ws + FEATS_B);
    float* x1 = partial + (size_t)S * 131072;
    float* x2 = x1 + 131072;
    hipLaunchKernelGGL(fft_feats_kernel, dim3(3, 256), dim3(512), 0, stream,
                       img, feats, W1, (unsigned short*)nullptr);
    hipLaunchKernelGGL(HIP_KERNEL_NAME(gemm1_kernel<false>), dim3(8, 2, S),
                       dim3(256), 0, stream, feats, (const void*)W1, partial, kchunk);
    hipLaunchKernelGGL(reduce1_kernel, dim3(512), dim3(256), 0, stream, partial, b1, x1, S);
    hipLaunchKernelGGL(fc2_kernel, dim3(256), dim3(256), 0, stream, x1, W2, b2, x2);
    hipLaunchKernelGGL(fc3_kernel, dim3(256), dim3(128), 0, stream, x2, W3, b3, out);
  }
}

// Round 4
// 213.973 us; speedup vs baseline: 1.1568x; 1.1568x over previous
//
#include <hip/hip_runtime.h>
#include <hip/hip_bf16.h>

#define IN_DIM 98304

typedef short bh8 __attribute__((ext_vector_type(8)));
typedef float f32x4 __attribute__((ext_vector_type(4)));
typedef unsigned short u16x8 __attribute__((ext_vector_type(8)));

__device__ __forceinline__ unsigned short f2bf(float f) {
  __hip_bfloat16 h = __float2bfloat16(f);
  return __builtin_bit_cast(unsigned short, h);
}

__device__ __forceinline__ void gload_lds16(const void* g, void* l) {
  __builtin_amdgcn_global_load_lds(
      (const __attribute__((address_space(1))) void*)g,
      (__attribute__((address_space(3))) void*)l, 16, 0, 0);
}

__device__ __forceinline__ void bfly(float2& a, float2& b, float wr, float wi) {
  float tr = wr * b.x - wi * b.y;
  float ti = wr * b.y + wi * b.x;
  b.x = a.x - tr; b.y = a.y - ti;
  a.x += tr; a.y += ti;
}

__device__ __forceinline__ float2 cmul(float2 a, float2 w) {
  return make_float2(a.x * w.x - a.y * w.y, a.x * w.y + a.y * w.x);
}

// 16-point FFT, input bit-reversed in v[], output natural order.
__device__ __forceinline__ void fft16(float2* v) {
  const float C8 = 0.70710678118654752f;
  const float C161 = 0.92387953251128674f, S161 = 0.38268343236508977f;
#pragma unroll
  for (int i = 0; i < 16; i += 2) bfly(v[i], v[i + 1], 1.f, 0.f);
#pragma unroll
  for (int i = 0; i < 16; i += 4) {
    bfly(v[i], v[i + 2], 1.f, 0.f);
    bfly(v[i + 1], v[i + 3], 0.f, -1.f);
  }
  {
    const float w8r[4] = {1.f, C8, 0.f, -C8};
    const float w8i[4] = {0.f, -C8, -1.f, -C8};
#pragma unroll
    for (int i = 0; i < 16; i += 8) {
#pragma unroll
      for (int j = 0; j < 4; ++j) bfly(v[i + j], v[i + j + 4], w8r[j], w8i[j]);
    }
  }
  {
    const float w16r[8] = {1.f, C161, C8, S161, 0.f, -S161, -C8, -C161};
    const float w16i[8] = {0.f, -S161, -C8, -C161, -1.f, -C161, -C8, -S161};
#pragma unroll
    for (int j = 0; j < 8; ++j) bfly(v[j], v[j + 8], w16r[j], w16i[j]);
  }
}

// 8-point FFT, input bit-reversed in v[], output natural order.
__device__ __forceinline__ void fft8(float2* v) {
  const float C8 = 0.70710678118654752f;
#pragma unroll
  for (int i = 0; i < 8; i += 2) bfly(v[i], v[i + 1], 1.f, 0.f);
#pragma unroll
  for (int i = 0; i < 8; i += 4) {
    bfly(v[i], v[i + 2], 1.f, 0.f);
    bfly(v[i + 1], v[i + 3], 0.f, -1.f);
  }
  bfly(v[0], v[4], 1.f, 0.f);
  bfly(v[1], v[5], C8, -C8);
  bfly(v[2], v[6], 0.f, -1.f);
  bfly(v[3], v[7], -C8, -C8);
}

// swizzled LDS index (float2 units)
__device__ __forceinline__ int IDX(int r, int cc) {
  return (r << 7) + (cc ^ ((r & 7) << 1));
}

// ---------------------------------------------------------------------------
// Kernel 1: 128x128 FFT2 + fftshift + amp/phase -> bf16 feats (R2 version).
// ---------------------------------------------------------------------------
__global__ __launch_bounds__(512) void fft_feats_kernel(
    const float* __restrict__ img, unsigned short* __restrict__ feats) {
  __shared__ float2 sm[16384];
  __shared__ float2 tw[128];
  const int tid = threadIdx.x;
  const int c = blockIdx.x, b = blockIdx.y;
  const float* src = img + ((size_t)(b * 3 + c) << 14);

  static const int BR4[16] = {0, 8, 4, 12, 2, 10, 6, 14, 1, 9, 5, 13, 3, 11, 7, 15};
  static const int BR3[8] = {0, 4, 2, 6, 1, 5, 3, 7};

  if (tid < 128) {
    float sv, cv;
    sincosf(-6.28318530717958647692f * (float)tid / 128.0f, &sv, &cv);
    tw[tid] = make_float2(cv, sv);
  }
  for (int i4 = tid; i4 < 4096; i4 += 512) {
    float4 x = *reinterpret_cast<const float4*>(src + (i4 << 2));
    int r = i4 >> 5, cc = (i4 << 2) & 127;
    *reinterpret_cast<float4*>(&sm[IDX(r, cc)]) = make_float4(x.x, 0.f, x.y, 0.f);
    *reinterpret_cast<float4*>(&sm[IDX(r, cc + 2)]) = make_float4(x.z, 0.f, x.w, 0.f);
  }
  __syncthreads();

  // ---- row pass, stage 1
#pragma unroll
  for (int it = 0; it < 2; ++it) {
    int ss = it * 512 + tid;
    int r = ss >> 3, n2 = ss & 7;
    float2 v[16];
#pragma unroll
    for (int j = 0; j < 16; ++j) v[j] = sm[IDX(r, (BR4[j] << 3) + n2)];
    fft16(v);
#pragma unroll
    for (int k1 = 1; k1 < 16; ++k1) v[k1] = cmul(v[k1], tw[n2 * k1]);
#pragma unroll
    for (int k1 = 0; k1 < 16; ++k1) sm[IDX(r, (k1 << 3) + n2)] = v[k1];
  }
  __syncthreads();

  // ---- row pass, stage 2
#pragma unroll
  for (int it = 0; it < 2; ++it) {
    int ss = it * 512 + tid;
    int r = ss >> 3, t8 = ss & 7;
    float2 u0[8], u1[8];
#pragma unroll
    for (int j = 0; j < 8; ++j) {
      u0[j] = sm[IDX(r, (t8 << 3) + BR3[j])];
      u1[j] = sm[IDX(r, ((t8 + 8) << 3) + BR3[j])];
    }
    __syncthreads();
    fft8(u0);
    fft8(u1);
#pragma unroll
    for (int k2 = 0; k2 < 8; ++k2) {
      sm[IDX(r, t8 + (k2 << 4))] = u0[k2];
      sm[IDX(r, t8 + 8 + (k2 << 4))] = u1[k2];
    }
  }
  __syncthreads();

  // ---- col pass, stage 1
#pragma unroll
  for (int it = 0; it < 2; ++it) {
    int ss = it * 512 + tid;
    int col = ss & 127, n2 = ss >> 7;
    float2 v[16];
#pragma unroll
    for (int j = 0; j < 16; ++j) v[j] = sm[IDX((BR4[j] << 3) + n2, col)];
    fft16(v);
#pragma unroll
    for (int k1 = 1; k1 < 16; ++k1) v[k1] = cmul(v[k1], tw[n2 * k1]);
#pragma unroll
    for (int k1 = 0; k1 < 16; ++k1) sm[IDX((k1 << 3) + n2, col)] = v[k1];
  }
  __syncthreads();

  // ---- col pass, stage 2 + fftshift + amp/phase + global write
  unsigned short* dst = feats + (size_t)b * IN_DIM + c * 32768;
#pragma unroll
  for (int it = 0; it < 2; ++it) {
    int ss = it * 512 + tid;
    int col = ss & 127, t8 = ss >> 7;
    float2 u0[8], u1[8];
#pragma unroll
    for (int j = 0; j < 8; ++j) {
      u0[j] = sm[IDX((t8 << 3) + BR3[j], col)];
      u1[j] = sm[IDX(((t8 + 8) << 3) + BR3[j], col)];
    }
    fft8(u0);
    fft8(u1);
    int ow = col ^ 64;
#pragma unroll
    for (int k2 = 0; k2 < 8; ++k2) {
      int oh0 = (t8 + (k2 << 4)) ^ 64;
      int oh1 = (t8 + 8 + (k2 << 4)) ^ 64;
      float a0 = sqrtf(u0[k2].x * u0[k2].x + u0[k2].y * u0[k2].y);
      float p0 = atan2f(u0[k2].y, u0[k2].x);
      float a1 = sqrtf(u1[k2].x * u1[k2].x + u1[k2].y * u1[k2].y);
      float p1 = atan2f(u1[k2].y, u1[k2].x);
      dst[(oh0 << 7) + ow] = f2bf(a0);
      dst[16384 + (oh0 << 7) + ow] = f2bf(p0);
      dst[(oh1 << 7) + ow] = f2bf(a1);
      dst[16384 + (oh1 << 7) + ow] = f2bf(p1);
    }
  }
}

// ---------------------------------------------------------------------------
// Kernel 2: layer-1 GEMM, split-K, counted-vmcnt pipeline (raw barriers).
// C[256x512] = feats(bf16) @ W1^T(fp32->bf16). Tile MT=256, NT=64, BK=32.
// grid 8*S blocks, XCD-aware decode so the 8 same-ks blocks share one L2.
// A: global_load_lds x4/wave/iter (linear LDS, conflict-free frag reads).
// B: reg-staged fp32->bf16 (compiler dataflow emits counted vmcnt).
// Main loop never drains vmcnt to 0: s_waitcnt vmcnt(6) + raw s_barrier.
// ---------------------------------------------------------------------------
__global__ __launch_bounds__(256, 3) void gemm1_kernel(
    const unsigned short* __restrict__ feats, const float* __restrict__ W1,
    float* __restrict__ partial, int S, int iters) {
  __shared__ __align__(16) unsigned short Asm[2][256 * 32];
  __shared__ __align__(16) unsigned short Bsm[2][64 * 32];
  const int tid = threadIdx.x;
  const int wv = tid >> 6, lane = tid & 63;

  // XCD-aware decode: blocks with the same ks land on the same XCD (f & 7).
  const int f = blockIdx.x;
  const int kpx = S >> 3;  // ks values per XCD
  const int xcd = f & 7, j = f >> 3;
  const int ks = kpx * xcd + (j % kpx);
  const int nt = j / kpx;
  const int n0 = nt * 64;
  const size_t k0 = (size_t)ks * ((size_t)iters * 32);

  f32x4 acc[4][4];
#pragma unroll
  for (int i = 0; i < 4; ++i)
#pragma unroll
    for (int jj = 0; jj < 4; ++jj) acc[i][jj] = (f32x4){0.f, 0.f, 0.f, 0.f};

  // A staging: chunk s = wv*4+t covers rows s*16..s*16+15; lane l -> LDS
  // linear s*1024B + l*16B <-> (row = s*16 + l/4, k16 = l&3).
  const int a_roff = lane >> 2;       // row within 16-row chunk
  const int a_k16 = (lane & 3) * 8;   // k element offset of this lane's 16B
  // B staging: thread -> (row rb, quarter q): 8 fp32 -> u16x8 -> ds_write.
  const int rb = tid >> 2, q = tid & 3;
  const float* wrow = W1 + (size_t)(n0 + rb) * IN_DIM + k0 + q * 8;

  auto stageA = [&](int buf, int it) {
    const size_t kb = k0 + (size_t)it * 32;
#pragma unroll
    for (int t = 0; t < 4; ++t) {
      const int s = wv * 4 + t;
      const unsigned short* g =
          feats + (size_t)(s * 16 + a_roff) * IN_DIM + kb + a_k16;
      gload_lds16(g, &Asm[buf][s * 512]);
    }
  };
  auto loadB = [&](int it, float4& v0, float4& v1) {
    const float* p = wrow + (size_t)it * 32;
    v0 = *reinterpret_cast<const float4*>(p);
    v1 = *reinterpret_cast<const float4*>(p + 4);
  };
  auto writeB = [&](int buf, const float4& v0, const float4& v1) {
    u16x8 bw;
    bw[0] = f2bf(v0.x); bw[1] = f2bf(v0.y); bw[2] = f2bf(v0.z); bw[3] = f2bf(v0.w);
    bw[4] = f2bf(v1.x); bw[5] = f2bf(v1.y); bw[6] = f2bf(v1.z); bw[7] = f2bf(v1.w);
    *reinterpret_cast<u16x8*>(&Bsm[buf][rb * 32 + q * 8]) = bw;
  };

  float4 bA0, bA1;  // B regs, parity 0
  float4 bB0, bB1;  // B regs, parity 1

  // prologue: tiles 0 and 1 in flight; B tile 0 in LDS.
  stageA(0, 0); loadB(0, bA0, bA1);
  stageA(1, 1); loadB(1, bB0, bB1);
  writeB(0, bA0, bA1);  // compiler waits bA regs via dataflow (counted vmcnt)

#define ITER_BODY(k, P, bPa, bPb, bQa, bQb)                                    \
  {                                                                            \
    if ((k) < iters - 1) {                                                     \
      asm volatile("s_waitcnt vmcnt(6) lgkmcnt(0)" ::: "memory");              \
    } else {                                                                   \
      asm volatile("s_waitcnt vmcnt(0) lgkmcnt(0)" ::: "memory");              \
    }                                                                          \
    __builtin_amdgcn_sched_barrier(0);                                         \
    __builtin_amdgcn_s_barrier();                                              \
    __builtin_amdgcn_sched_barrier(0);                                         \
    bh8 afr[4], bfr[4];                                                        \
    const int rm = lane & 15, ko = (lane >> 4) * 8;                            \
    _Pragma("unroll") for (int i = 0; i < 4; ++i)                              \
        afr[i] = *reinterpret_cast<const bh8*>(                                \
            &Asm[P][(wv * 64 + i * 16 + rm) * 32 + ko]);                       \
    _Pragma("unroll") for (int i = 0; i < 4; ++i)                              \
        bfr[i] = *reinterpret_cast<const bh8*>(&Bsm[P][(i * 16 + rm) * 32 + ko]); \
    asm volatile("s_waitcnt lgkmcnt(0)" ::: "memory");                         \
    __builtin_amdgcn_sched_barrier(0);                                         \
    __builtin_amdgcn_s_barrier();                                              \
    __builtin_amdgcn_sched_barrier(0);                                         \
    if ((k) + 2 < iters) { stageA(P, (k) + 2); loadB((k) + 2, bPa, bPb); }     \
    if ((k) + 1 < iters) { writeB((P) ^ 1, bQa, bQb); }                        \
    _Pragma("unroll") for (int i = 0; i < 4; ++i)                              \
        _Pragma("unroll") for (int jj = 0; jj < 4; ++jj)                       \
            acc[i][jj] = __builtin_amdgcn_mfma_f32_16x16x32_bf16(              \
                afr[i], bfr[jj], acc[i][jj], 0, 0, 0);                         \
  }

  for (int k2 = 0; k2 < iters; k2 += 2) {
    ITER_BODY(k2, 0, bA0, bA1, bB0, bB1);
    ITER_BODY(k2 + 1, 1, bB0, bB1, bA0, bA1);
  }
#undef ITER_BODY

  // epilogue: C/D layout col=lane&15, row=(lane>>4)*4+reg (m89-verified)
  const int rm = lane & 15, rg = lane >> 4;
  float* pbase = partial + ((size_t)ks << 17);
#pragma unroll
  for (int i = 0; i < 4; ++i) {
#pragma unroll
    for (int jj = 0; jj < 4; ++jj) {
      int n = n0 + jj * 16 + rm;
#pragma unroll
      for (int r = 0; r < 4; ++r) {
        int m = wv * 64 + i * 16 + rg * 4 + r;
        pbase[((size_t)m << 9) + n] = acc[i][jj][r];
      }
    }
  }
}

// ---------------------------------------------------------------------------
// Kernel 3: reduce split-K partials + bias + ReLU -> x1 [256][512] fp32
// ---------------------------------------------------------------------------
__global__ __launch_bounds__(256) void reduce1_kernel(
    const float* __restrict__ partial, const float* __restrict__ b1,
    float* __restrict__ x1, int S) {
  int i = blockIdx.x * 256 + threadIdx.x;  // 0..131071
  float s = b1[i & 511];
  for (int p = 0; p < S; ++p) s += partial[((size_t)p << 17) + i];
  x1[i] = fmaxf(s, 0.0f);
}

// ---------------------------------------------------------------------------
// Kernel 4: x2 = relu(x1 @ W2^T + b2)
// ---------------------------------------------------------------------------
__global__ __launch_bounds__(256) void fc2_kernel(
    const float* __restrict__ x1, const float* __restrict__ W2,
    const float* __restrict__ b2, float* __restrict__ x2) {
  __shared__ float xs[512];
  int b = blockIdx.x, n = threadIdx.x;
  xs[n] = x1[b * 512 + n];
  xs[n + 256] = x1[b * 512 + 256 + n];
  __syncthreads();
  float acc = b2[n];
  const float* wr = W2 + (size_t)n * 512;
#pragma unroll 4
  for (int k = 0; k < 512; k += 4) {
    float4 w = *reinterpret_cast<const float4*>(wr + k);
    acc += xs[k] * w.x + xs[k + 1] * w.y + xs[k + 2] * w.z + xs[k + 3] * w.w;
  }
  x2[b * 256 + n] = fmaxf(acc, 0.0f);
}

// ---------------------------------------------------------------------------
// Kernel 5: out = x2 @ W3^T + b3
// ---------------------------------------------------------------------------
__global__ __launch_bounds__(128) void fc3_kernel(
    const float* __restrict__ x2, const float* __restrict__ W3,
    const float* __restrict__ b3, float* __restrict__ out) {
  __shared__ float xs[256];
  int b = blockIdx.x, n = threadIdx.x;
  xs[n] = x2[b * 256 + n];
  xs[n + 128] = x2[b * 256 + 128 + n];
  __syncthreads();
  float acc = b3[n];
  const float* wr = W3 + (size_t)n * 256;
#pragma unroll 4
  for (int k = 0; k < 256; k += 4) {
    float4 w = *reinterpret_cast<const float4*>(wr + k);
    acc += xs[k] * w.x + xs[k + 1] * w.y + xs[k + 2] * w.z + xs[k + 3] * w.w;
  }
  out[b * 128 + n] = acc;
}

extern "C" void kernel_launch(void* const* d_in, const int* in_sizes, int n_in,
                              void* d_out, int out_size, void* d_ws, size_t ws_size,
                              hipStream_t stream) {
  const float* img = (const float*)d_in[0];
  const float* W1 = (const float*)d_in[1];
  const float* b1 = (const float*)d_in[2];
  const float* W2 = (const float*)d_in[3];
  const float* b2 = (const float*)d_in[4];
  const float* W3 = (const float*)d_in[5];
  const float* b3 = (const float*)d_in[6];
  float* out = (float*)d_out;
  char* ws = (char*)d_ws;

  const size_t FEATS_B = 50331648ull;  // bf16 [256][98304]
  const size_t TAIL_B = 524288ull + 262144ull;
  // pick the largest split-K S in {96, 64, 32} that fits ws
  int S = 32;
  if (ws_size >= FEATS_B + 96ull * 524288 + TAIL_B) S = 96;
  else if (ws_size >= FEATS_B + 64ull * 524288 + TAIL_B) S = 64;
  const int iters = IN_DIM / S / 32;  // 32 / 48 / 96 (all even)

  unsigned short* feats = (unsigned short*)ws;
  float* partial = (float*)(ws + FEATS_B);
  float* x1 = partial + (size_t)S * 131072;
  float* x2 = x1 + 131072;

  hipLaunchKernelGGL(fft_feats_kernel, dim3(3, 256), dim3(512), 0, stream, img, feats);
  hipLaunchKernelGGL(gemm1_kernel, dim3(8 * S), dim3(256), 0, stream,
                     feats, W1, partial, S, iters);
  hipLaunchKernelGGL(reduce1_kernel, dim3(512), dim3(256), 0, stream, partial, b1, x1, S);
  hipLaunchKernelGGL(fc2_kernel, dim3(256), dim3(256), 0, stream, x1, W2, b2, x2);
  hipLaunchKernelGGL(fc3_kernel, dim3(256), dim3(128), 0, stream, x2, W3, b3, out);
}